// Round 2
// baseline (29253.351 us; speedup 1.0000x reference)
//
#include <hip/hip_runtime.h>
#include <math.h>

#define Bsz 512
#define Tsz 2048
#define INsz 32
#define Hsz 256

typedef __attribute__((ext_vector_type(8))) _Float16 half8;
typedef __attribute__((ext_vector_type(4))) float f32x4;

__device__ __forceinline__ f32x4 mfma16h(half8 a, half8 b, f32x4 c) {
    return __builtin_amdgcn_mfma_f32_16x16x32_f16(a, b, c, 0, 0, 0);
}
__device__ __forceinline__ float fsigmoid(float x) { return 1.0f / (1.0f + __expf(-x)); }
__device__ __forceinline__ float ftanh(float x) {
    float e = __expf(-2.0f * fabsf(x));
    float r = (1.0f - e) / (1.0f + e);
    return copysignf(r, x);
}

// ---------------- ew0: pure function of x, fully parallel, fp32 ------------
__global__ void ew0k(const float* __restrict__ x, const float* __restrict__ Wev0,
                     const float* __restrict__ bev0, float* __restrict__ ew0p) {
    int idx = blockIdx.x * 256 + threadIdx.x;          // = b*T + t
    int t = idx & (Tsz - 1);
    float e = 0.0f;
    if (t > 0) {
        const float* xc = x + (size_t)idx * INsz;
        const float* xp = xc - INsz;
        float acc = bev0[0];
#pragma unroll
        for (int k = 0; k < INsz; ++k) acc += xc[k] * Wev0[k] + xp[k] * Wev0[INsz + k];
        e = fsigmoid(acc);
    }
    ew0p[idx] = e;
}

// ---------------- weight fragment prep: split-2 fp16 B-fragments ------------
// layout: dst[ ((tile*KC + kc)*2 + split)*512 + lane*8 + j ]
__global__ void prep_frag(const float* __restrict__ W, _Float16* __restrict__ dst, int KC) {
    int tile = blockIdx.x / KC, kc = blockIdx.x % KC;
    int lane = threadIdx.x;
    int n16 = lane & 15, q = lane >> 4;
#pragma unroll
    for (int j = 0; j < 8; ++j) {
        int k = kc * 32 + q * 8 + j;
        float wv = W[(size_t)k * Hsz + tile * 16 + n16];
        _Float16 hi = (_Float16)wv;
        _Float16 lo = (_Float16)(wv - (float)hi);
        size_t rec = ((size_t)tile * KC + kc) * 2;
        dst[(rec + 0) * 512 + lane * 8 + j] = hi;
        dst[(rec + 1) * 512 + lane * 8 + j] = lo;
    }
}

// ---------------- fused pipelined kernel ------------------------------------
// Launch L: role K0 -> chunk L, roles KB/EW1 -> chunk L-1, role K1 -> chunk L-2.
// Recurrence roles use a 3-barrier step: sA (h state) and sG (gated) are
// separate LDS buffers, removing the old overwrite barrier.
__global__ __launch_bounds__(512, 2) void fused(
    const float* __restrict__ x, const float* __restrict__ ew0p, float* __restrict__ ew1p,
    const _Float16* __restrict__ fA0, const _Float16* __restrict__ fR0, const _Float16* __restrict__ fI0,
    const _Float16* __restrict__ fA1, const _Float16* __restrict__ fR1,
    const _Float16* __restrict__ fI1, const _Float16* __restrict__ fS1,
    const float* __restrict__ bin0, const float* __restrict__ brec0, const float* __restrict__ battn0,
    const float* __restrict__ tau0, const float* __restrict__ gamma0, const float* __restrict__ beta0,
    const float* __restrict__ bin1, const float* __restrict__ brec1, const float* __restrict__ battn1,
    const float* __restrict__ tau1, const float* __restrict__ gamma1, const float* __restrict__ beta1,
    const float* __restrict__ bskip, const float* __restrict__ Wev1, const float* __restrict__ bev1,
    _Float16* __restrict__ h0nA, _Float16* __restrict__ h0nB,
    float* __restrict__ in1bA, float* __restrict__ in1bB,
    float* __restrict__ skpbA, float* __restrict__ skpbB,
    float* __restrict__ h1s, int C, int L, int nch) {

    __shared__ _Float16 sAh[4096], sAl[4096];   // h state (hi/lo planes)
    __shared__ _Float16 sGh[4096], sGl[4096];   // gated h (hi/lo planes)
    __shared__ _Float16 sW[32768];              // attn hi plane, tiles 0-7 (64 KB)
    __shared__ float red[16][8][2];

    const int tid = threadIdx.x;
    const int w = tid >> 6, lane = tid & 63;
    const int n16 = lane & 15, q = lane >> 4;
    const int bx = blockIdx.x;

    if (bx < 32) {
        // ================= role K0: layer-0 recurrence, chunk L ============
        const int ci = L;
        if (ci >= nch) return;
        _Float16* __restrict__ h0n = (ci & 1) ? h0nB : h0nA;
        const _Float16* __restrict__ h0prev = (ci & 1) ? h0nA : h0nB;
        const int t0 = ci * C;
        const int rb = bx;
        const int r0 = rb * 16;
        const int c0 = w * 16 + n16, c1 = c0 + 128;

        // sW <- hi plane of tiles 0..7 (rec = tile*8+kc, 64 int4 per rec)
        for (int i = tid; i < 4096; i += 512) {
            int rec = i >> 6, off = i & 63;
            ((int4*)sW)[i] = ((const int4*)(fA0 + (size_t)rec * 2 * 512))[off];
        }
        half8 rB[2][8][2];
#pragma unroll
        for (int t2 = 0; t2 < 2; ++t2) {
            const int tile = t2 ? w + 8 : w;
#pragma unroll
            for (int kc = 0; kc < 8; ++kc) {
#pragma unroll
                for (int sp = 0; sp < 2; ++sp)
                    rB[t2][kc][sp] = *(const half8*)(fR0 + (((size_t)tile * 8 + kc) * 2 + sp) * 512 + lane * 8);
            }
        }
        half8 iB[2][2];
#pragma unroll
        for (int t2 = 0; t2 < 2; ++t2) {
            const int tile = t2 ? w + 8 : w;
#pragma unroll
            for (int sp = 0; sp < 2; ++sp)
                iB[t2][sp] = *(const half8*)(fI0 + ((size_t)tile * 2 + sp) * 512 + lane * 8);
        }
        float cbi[2], cbr[2], cba[2], ctau[2], cg[2], cb[2];
#pragma unroll
        for (int t2 = 0; t2 < 2; ++t2) {
            const int col = t2 ? c1 : c0;
            cbi[t2] = bin0[col]; cbr[t2] = brec0[col]; cba[t2] = battn0[col];
            ctau[t2] = 0.1f / fminf(fmaxf(tau0[col], 0.1f), 10.0f);
            cg[t2] = gamma0[col]; cb[t2] = beta0[col];
        }
        // init: prev-buffer slot C = h0 state at t0-1; copy to slot 0 of cur
        {
            const int4* src = (const int4*)(h0prev + ((size_t)C * 32 + rb) * 8192);
            int4 vh = src[tid], vl = src[tid + 512];
            ((int4*)sAh)[tid] = vh; ((int4*)sAl)[tid] = vl;
            int4* dst0 = (int4*)(h0n + (size_t)rb * 8192);
            dst0[tid] = vh; dst0[tid + 512] = vl;
        }
        __syncthreads();
        float h0reg[2][4];
#pragma unroll
        for (int t2 = 0; t2 < 2; ++t2) {
            const int col = t2 ? c1 : c0;
#pragma unroll
            for (int r = 0; r < 4; ++r) {
                int idx = ((col >> 3) * 16 + (q * 4 + r)) * 8 + (col & 7);
                h0reg[t2][r] = (float)sAh[idx] + (float)sAl[idx];
            }
        }
        auto pwA = [&](int row, int col, float v) {
            int idx = ((col >> 3) * 16 + row) * 8 + (col & 7);
            _Float16 h = (_Float16)v;
            sAh[idx] = h;
            sAl[idx] = (_Float16)(v - (float)h);
        };
        auto pwG = [&](int row, int col, float v) {
            int idx = ((col >> 3) * 16 + row) * 8 + (col & 7);
            _Float16 h = (_Float16)v;
            sGh[idx] = h;
            sGl[idx] = (_Float16)(v - (float)h);
        };

        const float* xbase = x + (size_t)(r0 + n16) * Tsz * INsz;
        const _Float16* lo0 = fA0 + ((size_t)w * 8 * 2 + 1) * 512 + lane * 8;          // tile w lo
        const _Float16* hi1 = fA0 + ((size_t)(w + 8) * 8 * 2 + 0) * 512 + lane * 8;    // tile w+8 hi
        const _Float16* lo1 = fA0 + ((size_t)(w + 8) * 8 * 2 + 1) * 512 + lane * 8;    // tile w+8 lo

        // software pipeline: x raw float4 and ew0 loaded 1 step ahead
        float4 xv0 = *(const float4*)(xbase + (size_t)t0 * INsz + q * 8);
        float4 xv1 = *(const float4*)(xbase + (size_t)t0 * INsz + q * 8 + 4);
        float e0r[4];
#pragma unroll
        for (int r = 0; r < 4; ++r)
            e0r[r] = ew0p[(size_t)(r0 + q * 4 + r) * Tsz + t0];

#pragma unroll 1
        for (int s = 0; s < C; ++s) {
            const int t = t0 + s;
            // convert prefetched x(t), then issue x(t+1)
            half8 xh, xl;
            {
                float xv[8] = {xv0.x, xv0.y, xv0.z, xv0.w, xv1.x, xv1.y, xv1.z, xv1.w};
#pragma unroll
                for (int j = 0; j < 8; ++j) {
                    _Float16 h = (_Float16)xv[j];
                    xh[j] = h;
                    xl[j] = (_Float16)(xv[j] - (float)h);
                }
            }
            if (s + 1 < C) {
                const float* xp = xbase + (size_t)(t + 1) * INsz + q * 8;
                xv0 = *(const float4*)xp;
                xv1 = *(const float4*)(xp + 4);
            }
            // ---- phase A: mm_attn (A = sA = h_{t-1}) + inp; gate -> sG ----
            f32x4 aA0 = {0,0,0,0}, aA1 = {0,0,0,0};
            {
                half8 nl0 = *(const half8*)(lo0);
                half8 nh1 = *(const half8*)(hi1);
                half8 nl1 = *(const half8*)(lo1);
#pragma unroll
                for (int kc = 0; kc < 8; ++kc) {
                    half8 cl0 = nl0, ch1 = nh1, cl1 = nl1;
                    if (kc < 7) {
                        nl0 = *(const half8*)(lo0 + (size_t)(kc + 1) * 2 * 512);
                        nh1 = *(const half8*)(hi1 + (size_t)(kc + 1) * 2 * 512);
                        nl1 = *(const half8*)(lo1 + (size_t)(kc + 1) * 2 * 512);
                    }
                    half8 ah = *(const half8*)&sAh[((kc * 4 + q) * 16 + n16) * 8];
                    half8 al = *(const half8*)&sAl[((kc * 4 + q) * 16 + n16) * 8];
                    half8 bh0 = *(const half8*)&sW[((w * 8 + kc) * 512) + lane * 8];
                    aA0 = mfma16h(ah, bh0, aA0); aA1 = mfma16h(ah, ch1, aA1);
                    aA0 = mfma16h(al, bh0, aA0); aA1 = mfma16h(al, ch1, aA1);
                    aA0 = mfma16h(ah, cl0, aA0); aA1 = mfma16h(ah, cl1, aA1);
                    aA0 = mfma16h(al, cl0, aA0); aA1 = mfma16h(al, cl1, aA1);
                }
            }
            f32x4 aI0 = {0,0,0,0}, aI1 = {0,0,0,0};
            aI0 = mfma16h(xh, iB[0][0], aI0); aI1 = mfma16h(xh, iB[1][0], aI1);
            aI0 = mfma16h(xl, iB[0][0], aI0); aI1 = mfma16h(xl, iB[1][0], aI1);
            aI0 = mfma16h(xh, iB[0][1], aI0); aI1 = mfma16h(xh, iB[1][1], aI1);
            aI0 = mfma16h(xl, iB[0][1], aI0); aI1 = mfma16h(xl, iB[1][1], aI1);
#pragma unroll
            for (int r = 0; r < 4; ++r) {
                const int row = q * 4 + r;
                pwG(row, c0, h0reg[0][r] * fsigmoid(aA0[r] + cba[0]));
                pwG(row, c1, h0reg[1][r] * fsigmoid(aA1[r] + cba[1]));
            }
            __syncthreads();   // BAR1: sG ready (sA reads also complete)
            // ---- phase B: mm_rec (A = sG), cell, LN partial reduce --------
            f32x4 aR0 = {0,0,0,0}, aR1 = {0,0,0,0};
#pragma unroll
            for (int kc = 0; kc < 8; ++kc) {
                half8 ah = *(const half8*)&sGh[((kc * 4 + q) * 16 + n16) * 8];
                half8 al = *(const half8*)&sGl[((kc * 4 + q) * 16 + n16) * 8];
                aR0 = mfma16h(ah, rB[0][kc][0], aR0); aR1 = mfma16h(ah, rB[1][kc][0], aR1);
                aR0 = mfma16h(al, rB[0][kc][0], aR0); aR1 = mfma16h(al, rB[1][kc][0], aR1);
                aR0 = mfma16h(ah, rB[0][kc][1], aR0); aR1 = mfma16h(ah, rB[1][kc][1], aR1);
                aR0 = mfma16h(al, rB[0][kc][1], aR0); aR1 = mfma16h(al, rB[1][kc][1], aR1);
            }
            float cell[2][4];
#pragma unroll
            for (int r = 0; r < 4; ++r) {
                float i0 = ftanh(aI0[r] + cbi[0]);
                float i1 = ftanh(aI1[r] + cbi[1]);
                float g0 = ftanh(aR0[r] + cbr[0]);
                float g1 = ftanh(aR1[r] + cbr[1]);
                float ef = 1.0f + e0r[r];
                cell[0][r] = h0reg[0][r] + ctau[0] * ef * (i0 + g0 - h0reg[0][r]);
                cell[1][r] = h0reg[1][r] + ctau[1] * ef * (i1 + g1 - h0reg[1][r]);
            }
            // prefetch next-step ew0 now (hidden across BAR2/BAR3/store)
            if (s + 1 < C) {
#pragma unroll
                for (int r = 0; r < 4; ++r)
                    e0r[r] = ew0p[(size_t)(r0 + q * 4 + r) * Tsz + t + 1];
            }
#pragma unroll
            for (int r = 0; r < 4; ++r) {
                float pr = cell[0][r] + cell[1][r];
                float p2 = cell[0][r] * cell[0][r] + cell[1][r] * cell[1][r];
#pragma unroll
                for (int off = 1; off < 16; off <<= 1) {
                    pr += __shfl_xor(pr, off, 64);
                    p2 += __shfl_xor(p2, off, 64);
                }
                if (n16 == 0) { red[q * 4 + r][w][0] = pr; red[q * 4 + r][w][1] = p2; }
            }
            __syncthreads();   // BAR2: red ready
            // ---- phase C: LN finalize, h_t -> sA, store ------------------
            float lnm[4], lnr[4];
#pragma unroll
            for (int r = 0; r < 4; ++r) {
                const int row = q * 4 + r;
                float S = 0.0f, Q2 = 0.0f;
#pragma unroll
                for (int wv = 0; wv < 8; ++wv) { S += red[row][wv][0]; Q2 += red[row][wv][1]; }
                float mu = S * (1.0f / 256.0f);
                float var = Q2 * (1.0f / 256.0f) - mu * mu;
                lnm[r] = mu;
                lnr[r] = 1.0f / sqrtf(var + 1e-5f);
            }
#pragma unroll
            for (int r = 0; r < 4; ++r) {
                const int row = q * 4 + r;
                float h0v = (cell[0][r] - lnm[r]) * lnr[r] * cg[0] + cb[0];
                float h1v = (cell[1][r] - lnm[r]) * lnr[r] * cg[1] + cb[1];
                pwA(row, c0, h0v); pwA(row, c1, h1v);
                h0reg[0][r] = h0v; h0reg[1][r] = h1v;
            }
            __syncthreads();   // BAR3: sA = h_t
            int4* d = (int4*)(h0n + ((size_t)(s + 1) * 32 + rb) * 8192);
            d[tid] = ((const int4*)sAh)[tid];
            d[tid + 512] = ((const int4*)sAl)[tid];
        }
    } else if (bx < 64) {
        // ================= role K1: layer-1 recurrence, chunk L-2 ==========
        const int ci = L - 2;
        if (ci < 0) return;
        const float* __restrict__ in1b = (ci & 1) ? in1bB : in1bA;
        const float* __restrict__ skpb = (ci & 1) ? skpbB : skpbA;
        const int t0 = ci * C;
        const int rb = bx - 32;
        const int r0 = rb * 16;
        const int c0 = w * 16 + n16, c1 = c0 + 128;

        for (int i = tid; i < 4096; i += 512) {
            int rec = i >> 6, off = i & 63;
            ((int4*)sW)[i] = ((const int4*)(fA1 + (size_t)rec * 2 * 512))[off];
        }
        half8 rB[2][8][2];
#pragma unroll
        for (int t2 = 0; t2 < 2; ++t2) {
            const int tile = t2 ? w + 8 : w;
#pragma unroll
            for (int kc = 0; kc < 8; ++kc) {
#pragma unroll
                for (int sp = 0; sp < 2; ++sp)
                    rB[t2][kc][sp] = *(const half8*)(fR1 + (((size_t)tile * 8 + kc) * 2 + sp) * 512 + lane * 8);
            }
        }
        float cbr[2], cba[2], ctau[2], cg[2], cb[2];
#pragma unroll
        for (int t2 = 0; t2 < 2; ++t2) {
            const int col = t2 ? c1 : c0;
            cbr[t2] = brec1[col]; cba[t2] = battn1[col];
            ctau[t2] = 0.1f / fminf(fmaxf(tau1[col], 0.1f), 10.0f);
            cg[t2] = gamma1[col]; cb[t2] = beta1[col];
        }
        float h1reg[2][4];
#pragma unroll
        for (int t2 = 0; t2 < 2; ++t2) {
            const int col = t2 ? c1 : c0;
#pragma unroll
            for (int r = 0; r < 4; ++r) {
                const int row = q * 4 + r;
                float hv = h1s[(size_t)(r0 + row) * Hsz + col];
                h1reg[t2][r] = hv;
                int idx = ((col >> 3) * 16 + row) * 8 + (col & 7);
                _Float16 h = (_Float16)hv;
                sAh[idx] = h;
                sAl[idx] = (_Float16)(hv - (float)h);
            }
        }
        __syncthreads();

        auto pwA = [&](int row, int col, float v) {
            int idx = ((col >> 3) * 16 + row) * 8 + (col & 7);
            _Float16 h = (_Float16)v;
            sAh[idx] = h;
            sAl[idx] = (_Float16)(v - (float)h);
        };
        auto pwG = [&](int row, int col, float v) {
            int idx = ((col >> 3) * 16 + row) * 8 + (col & 7);
            _Float16 h = (_Float16)v;
            sGh[idx] = h;
            sGl[idx] = (_Float16)(v - (float)h);
        };
        const _Float16* lo0 = fA1 + ((size_t)w * 8 * 2 + 1) * 512 + lane * 8;
        const _Float16* hi1 = fA1 + ((size_t)(w + 8) * 8 * 2 + 0) * 512 + lane * 8;
        const _Float16* lo1 = fA1 + ((size_t)(w + 8) * 8 * 2 + 1) * 512 + lane * 8;

        float e1r[4];
#pragma unroll
        for (int r = 0; r < 4; ++r)
            e1r[r] = ew1p[(size_t)(r0 + q * 4 + r) * Tsz + t0];

#pragma unroll 1
        for (int s = 0; s < C; ++s) {
            const int t = t0 + s;
            float iv[2][4], sv[2][4];
#pragma unroll
            for (int r = 0; r < 4; ++r) {
                const int row = q * 4 + r;
                size_t i0 = ((size_t)s * Bsz + r0 + row) * Hsz + c0;
                size_t i1 = ((size_t)s * Bsz + r0 + row) * Hsz + c1;
                iv[0][r] = in1b[i0]; iv[1][r] = in1b[i1];
                sv[0][r] = skpb[i0]; sv[1][r] = skpb[i1];
            }
            // ---- phase A: mm_attn1 (A = sA = h1_{t-1}); gate -> sG --------
            f32x4 aA0 = {0,0,0,0}, aA1 = {0,0,0,0};
            {
                half8 nl0 = *(const half8*)(lo0);
                half8 nh1 = *(const half8*)(hi1);
                half8 nl1 = *(const half8*)(lo1);
#pragma unroll
                for (int kc = 0; kc < 8; ++kc) {
                    half8 cl0 = nl0, ch1 = nh1, cl1 = nl1;
                    if (kc < 7) {
                        nl0 = *(const half8*)(lo0 + (size_t)(kc + 1) * 2 * 512);
                        nh1 = *(const half8*)(hi1 + (size_t)(kc + 1) * 2 * 512);
                        nl1 = *(const half8*)(lo1 + (size_t)(kc + 1) * 2 * 512);
                    }
                    half8 ah = *(const half8*)&sAh[((kc * 4 + q) * 16 + n16) * 8];
                    half8 al = *(const half8*)&sAl[((kc * 4 + q) * 16 + n16) * 8];
                    half8 bh0 = *(const half8*)&sW[((w * 8 + kc) * 512) + lane * 8];
                    aA0 = mfma16h(ah, bh0, aA0); aA1 = mfma16h(ah, ch1, aA1);
                    aA0 = mfma16h(al, bh0, aA0); aA1 = mfma16h(al, ch1, aA1);
                    aA0 = mfma16h(ah, cl0, aA0); aA1 = mfma16h(ah, cl1, aA1);
                    aA0 = mfma16h(al, cl0, aA0); aA1 = mfma16h(al, cl1, aA1);
                }
            }
#pragma unroll
            for (int r = 0; r < 4; ++r) {
                const int row = q * 4 + r;
                pwG(row, c0, h1reg[0][r] * fsigmoid(aA0[r] + cba[0]));
                pwG(row, c1, h1reg[1][r] * fsigmoid(aA1[r] + cba[1]));
            }
            __syncthreads();   // BAR1
            // ---- phase B: mm_rec1 (A = sG), cell, LN partial reduce -------
            f32x4 aR0 = {0,0,0,0}, aR1 = {0,0,0,0};
#pragma unroll
            for (int kc = 0; kc < 8; ++kc) {
                half8 ah = *(const half8*)&sGh[((kc * 4 + q) * 16 + n16) * 8];
                half8 al = *(const half8*)&sGl[((kc * 4 + q) * 16 + n16) * 8];
                aR0 = mfma16h(ah, rB[0][kc][0], aR0); aR1 = mfma16h(ah, rB[1][kc][0], aR1);
                aR0 = mfma16h(al, rB[0][kc][0], aR0); aR1 = mfma16h(al, rB[1][kc][0], aR1);
                aR0 = mfma16h(ah, rB[0][kc][1], aR0); aR1 = mfma16h(ah, rB[1][kc][1], aR1);
                aR0 = mfma16h(al, rB[0][kc][1], aR0); aR1 = mfma16h(al, rB[1][kc][1], aR1);
            }
            float cell[2][4];
#pragma unroll
            for (int r = 0; r < 4; ++r) {
                float g0 = ftanh(aR0[r] + cbr[0]);
                float g1 = ftanh(aR1[r] + cbr[1]);
                float ef = 1.0f + e1r[r];
                cell[0][r] = h1reg[0][r] + ctau[0] * ef * (iv[0][r] + g0 - h1reg[0][r]);
                cell[1][r] = h1reg[1][r] + ctau[1] * ef * (iv[1][r] + g1 - h1reg[1][r]);
            }
            if (s + 1 < C) {
#pragma unroll
                for (int r = 0; r < 4; ++r)
                    e1r[r] = ew1p[(size_t)(r0 + q * 4 + r) * Tsz + t + 1];
            }
#pragma unroll
            for (int r = 0; r < 4; ++r) {
                float pr = cell[0][r] + cell[1][r];
                float p2 = cell[0][r] * cell[0][r] + cell[1][r] * cell[1][r];
#pragma unroll
                for (int off = 1; off < 16; off <<= 1) {
                    pr += __shfl_xor(pr, off, 64);
                    p2 += __shfl_xor(p2, off, 64);
                }
                if (n16 == 0) { red[q * 4 + r][w][0] = pr; red[q * 4 + r][w][1] = p2; }
            }
            __syncthreads();   // BAR2
            // ---- phase C ---------------------------------------------------
            float lnm[4], lnr[4];
#pragma unroll
            for (int r = 0; r < 4; ++r) {
                const int row = q * 4 + r;
                float S = 0.0f, Q2 = 0.0f;
#pragma unroll
                for (int wv = 0; wv < 8; ++wv) { S += red[row][wv][0]; Q2 += red[row][wv][1]; }
                float mu = S * (1.0f / 256.0f);
                float var = Q2 * (1.0f / 256.0f) - mu * mu;
                lnm[r] = mu;
                lnr[r] = 1.0f / sqrtf(var + 1e-5f);
            }
#pragma unroll
            for (int r = 0; r < 4; ++r) {
                const int row = q * 4 + r;
                float h0v = (cell[0][r] - lnm[r]) * lnr[r] * cg[0] + cb[0] + sv[0][r];
                float h1v = (cell[1][r] - lnm[r]) * lnr[r] * cg[1] + cb[1] + sv[1][r];
                pwA(row, c0, h0v); pwA(row, c1, h1v);
                h1reg[0][r] = h0v; h1reg[1][r] = h1v;
            }
            __syncthreads();   // BAR3
        }
        // persist fp32 h1 state
#pragma unroll
        for (int t2 = 0; t2 < 2; ++t2) {
            const int col = t2 ? c1 : c0;
#pragma unroll
            for (int r = 0; r < 4; ++r)
                h1s[(size_t)(r0 + q * 4 + r) * Hsz + col] = h1reg[t2][r];
        }
    } else if (bx < 64 + C * 4) {
        // ================= role KB: in1/skip GEMMs, chunk L-1 ==============
        const int ci = L - 1;
        if (ci < 0 || ci >= nch) return;
        const _Float16* __restrict__ h0n = (ci & 1) ? h0nB : h0nA;
        float* __restrict__ in1b = (ci & 1) ? in1bB : in1bA;
        float* __restrict__ skpb = (ci & 1) ? skpbB : skpbA;
        const int bi = bx - 64;
        const int sbase = (bi >> 5) * 8;
        const int rb = bi & 31;
        const int r0 = rb * 16;
        const int c0 = w * 16 + n16, c1 = c0 + 128;
        float cbi[2], cbs[2];
#pragma unroll
        for (int t2 = 0; t2 < 2; ++t2) {
            const int col = t2 ? c1 : c0;
            cbi[t2] = bin1[col]; cbs[t2] = bskip[col];
        }
        for (int i = 0; i < 8; ++i) {
            const int s = sbase + i;
            const _Float16* abase = h0n + ((size_t)(s + 1) * 32 + rb) * 8192;
            f32x4 aI0 = {0,0,0,0}, aI1 = {0,0,0,0}, aS0 = {0,0,0,0}, aS1 = {0,0,0,0};
#pragma unroll
            for (int kc = 0; kc < 8; ++kc) {
                half8 ah = *(const half8*)&abase[((kc * 4 + q) * 16 + n16) * 8];
                half8 al = *(const half8*)&abase[4096 + ((kc * 4 + q) * 16 + n16) * 8];
                size_t o0 = (((size_t)w * 8 + kc) * 2) * 512 + lane * 8;
                size_t o1 = (((size_t)(w + 8) * 8 + kc) * 2) * 512 + lane * 8;
                half8 bh0 = *(const half8*)(fI1 + o0), bl0 = *(const half8*)(fI1 + o0 + 512);
                half8 bh1 = *(const half8*)(fI1 + o1), bl1 = *(const half8*)(fI1 + o1 + 512);
                aI0 = mfma16h(ah, bh0, aI0); aI1 = mfma16h(ah, bh1, aI1);
                aI0 = mfma16h(al, bh0, aI0); aI1 = mfma16h(al, bh1, aI1);
                aI0 = mfma16h(ah, bl0, aI0); aI1 = mfma16h(ah, bl1, aI1);
                aI0 = mfma16h(al, bl0, aI0); aI1 = mfma16h(al, bl1, aI1);
                half8 ch0 = *(const half8*)(fS1 + o0), cl0 = *(const half8*)(fS1 + o0 + 512);
                half8 ch1 = *(const half8*)(fS1 + o1), cl1 = *(const half8*)(fS1 + o1 + 512);
                aS0 = mfma16h(ah, ch0, aS0); aS1 = mfma16h(ah, ch1, aS1);
                aS0 = mfma16h(al, ch0, aS0); aS1 = mfma16h(al, ch1, aS1);
                aS0 = mfma16h(ah, cl0, aS0); aS1 = mfma16h(ah, cl1, aS1);
                aS0 = mfma16h(al, cl0, aS0); aS1 = mfma16h(al, cl1, aS1);
            }
#pragma unroll
            for (int r = 0; r < 4; ++r) {
                const int row = q * 4 + r;
                size_t i0 = ((size_t)s * Bsz + r0 + row) * Hsz + c0;
                size_t i1 = ((size_t)s * Bsz + r0 + row) * Hsz + c1;
                in1b[i0] = ftanh(aI0[r] + cbi[0]);
                in1b[i1] = ftanh(aI1[r] + cbi[1]);
                skpb[i0] = aS0[r] + cbs[0];
                skpb[i1] = aS1[r] + cbs[1];
            }
        }
    } else {
        // ================= role EW1: event weights, chunk L-1 ==============
        const int ci = L - 1;
        if (ci < 0 || ci >= nch) return;
        const _Float16* __restrict__ h0n = (ci & 1) ? h0nB : h0nA;
        const int t0 = ci * C;
        const int bi = bx - 64 - C * 4;
        const int wid = bi * 8 + w;
        const int s = wid >> 5, rb = wid & 31;
        float acc = 0.0f;
#pragma unroll
        for (int half = 0; half < 2; ++half) {
            const _Float16* base = h0n + ((size_t)(half ? s : s + 1) * 32 + rb) * 8192;
#pragma unroll
            for (int kc = 0; kc < 8; ++kc) {
                half8 ah = *(const half8*)&base[((kc * 4 + q) * 16 + n16) * 8];
                half8 al = *(const half8*)&base[4096 + ((kc * 4 + q) * 16 + n16) * 8];
                const float* wv = Wev1 + half * 256 + kc * 32 + q * 8;
#pragma unroll
                for (int j = 0; j < 8; ++j)
                    acc += ((float)ah[j] + (float)al[j]) * wv[j];
            }
        }
        acc += __shfl_xor(acc, 16, 64);
        acc += __shfl_xor(acc, 32, 64);
        const int t = t0 + s;
        if (q == 0) {
            float e = (t > 0) ? fsigmoid(acc + bev1[0]) : 0.0f;
            ew1p[(size_t)(rb * 16 + n16) * Tsz + t] = e;
        }
    }
}

// ---------------- out = h1_final @ Wout + bout ------------------------------
__global__ void outk(const float* __restrict__ h1s, const float* __restrict__ Wout,
                     const float* __restrict__ bout, float* __restrict__ outp) {
    const int w = threadIdx.x >> 6, lane = threadIdx.x & 63;
    const int b = blockIdx.x * 4 + w;
    float4 hv = *(const float4*)(h1s + (size_t)b * Hsz + lane * 4);
    float4 wv = *(const float4*)(Wout + lane * 4);
    float acc = hv.x * wv.x + hv.y * wv.y + hv.z * wv.z + hv.w * wv.w;
#pragma unroll
    for (int off = 1; off < 64; off <<= 1) acc += __shfl_xor(acc, off, 64);
    if (lane == 0) outp[b] = acc + bout[0];
}

extern "C" void kernel_launch(void* const* d_in, const int* in_sizes, int n_in,
                              void* d_out, int out_size, void* d_ws, size_t ws_size,
                              hipStream_t stream) {
    const float* x      = (const float*)d_in[0];
    const float* Win0   = (const float*)d_in[1];
    const float* bin0   = (const float*)d_in[2];
    const float* Wrec0  = (const float*)d_in[3];
    const float* brec0  = (const float*)d_in[4];
    const float* Wattn0 = (const float*)d_in[5];
    const float* battn0 = (const float*)d_in[6];
    const float* Wev0   = (const float*)d_in[7];
    const float* bev0   = (const float*)d_in[8];
    const float* tau0   = (const float*)d_in[9];
    const float* gamma0 = (const float*)d_in[10];
    const float* beta0  = (const float*)d_in[11];
    const float* Win1   = (const float*)d_in[12];
    const float* bin1   = (const float*)d_in[13];
    const float* Wrec1  = (const float*)d_in[14];
    const float* brec1  = (const float*)d_in[15];
    const float* Wattn1 = (const float*)d_in[16];
    const float* battn1 = (const float*)d_in[17];
    const float* Wev1   = (const float*)d_in[18];
    const float* bev1   = (const float*)d_in[19];
    const float* tau1   = (const float*)d_in[20];
    const float* gamma1 = (const float*)d_in[21];
    const float* beta1  = (const float*)d_in[22];
    const float* Wskip  = (const float*)d_in[23];
    const float* bskip  = (const float*)d_in[24];
    const float* Wout   = (const float*)d_in[25];
    const float* bout   = (const float*)d_in[26];

    float* outp = (float*)d_out;
    float* ew0p = outp + Bsz;                       // ew0 [B,T]
    float* ew1p = ew0p + (size_t)Bsz * Tsz;         // ew1 [B,T]

    // ---- workspace layout ----
    // fragments | h0n x2 (ping-pong) | in1b x2 | skpb x2 | h1s
    _Float16* p = (_Float16*)d_ws;
    _Float16* fA0 = p; p += 131072;
    _Float16* fR0 = p; p += 131072;
    _Float16* fA1 = p; p += 131072;
    _Float16* fR1 = p; p += 131072;
    _Float16* fI1 = p; p += 131072;
    _Float16* fS1 = p; p += 131072;
    _Float16* fI0 = p; p += 16384;
    size_t frag_bytes = (size_t)(6 * 131072 + 16384) * 2;

    int C = 64;
    while (C > 16) {
        size_t need = frag_bytes
                    + 2 * ((size_t)(C + 1) * 524288)   // h0n x2
                    + 4 * ((size_t)C * 524288)          // in1b x2 + skpb x2
                    + 524288;                           // h1s
        if (need <= ws_size) break;
        C >>= 1;
    }
    char* qp = (char*)d_ws + frag_bytes;
    _Float16* h0nA = (_Float16*)qp; qp += (size_t)(C + 1) * 524288;
    _Float16* h0nB = (_Float16*)qp; qp += (size_t)(C + 1) * 524288;
    float* in1bA = (float*)qp;      qp += (size_t)C * 524288;
    float* in1bB = (float*)qp;      qp += (size_t)C * 524288;
    float* skpbA = (float*)qp;      qp += (size_t)C * 524288;
    float* skpbB = (float*)qp;      qp += (size_t)C * 524288;
    float* h1s = (float*)qp;
    (void)in_sizes; (void)n_in; (void)out_size;

    // chunk 0 reads its init state from h0nB slot C -> zero it; zero h1 state
    hipMemsetAsync(h0nB + (size_t)C * 32 * 8192, 0, 524288, stream);
    hipMemsetAsync(h1s, 0, 524288, stream);

    ew0k<<<(Bsz * Tsz) / 256, 256, 0, stream>>>(x, Wev0, bev0, ew0p);
    prep_frag<<<16 * 8, 64, 0, stream>>>(Wattn0, fA0, 8);
    prep_frag<<<16 * 8, 64, 0, stream>>>(Wrec0,  fR0, 8);
    prep_frag<<<16 * 8, 64, 0, stream>>>(Wattn1, fA1, 8);
    prep_frag<<<16 * 8, 64, 0, stream>>>(Wrec1,  fR1, 8);
    prep_frag<<<16 * 8, 64, 0, stream>>>(Win1,   fI1, 8);
    prep_frag<<<16 * 8, 64, 0, stream>>>(Wskip,  fS1, 8);
    prep_frag<<<16 * 1, 64, 0, stream>>>(Win0,   fI0, 1);

    const int nch = Tsz / C;
    const int grid = 64 + C * 8;    // 32 k0 + 32 k1 + 4C kb + 4C ew1
    for (int L = 0; L < nch + 2; ++L) {
        fused<<<grid, 512, 0, stream>>>(
            x, ew0p, ew1p, fA0, fR0, fI0, fA1, fR1, fI1, fS1,
            bin0, brec0, battn0, tau0, gamma0, beta0,
            bin1, brec1, battn1, tau1, gamma1, beta1,
            bskip, Wev1, bev1,
            h0nA, h0nB, in1bA, in1bB, skpbA, skpbB, h1s, C, L, nch);
    }
    outk<<<Bsz / 4, 256, 0, stream>>>(h1s, Wout, bout, outp);
}

// Round 3
// 22562.373 us; speedup vs baseline: 1.2966x; 1.2966x over previous
//
#include <hip/hip_runtime.h>
#include <math.h>

#define Bsz 512
#define Tsz 2048
#define INsz 32
#define Hsz 256

typedef __attribute__((ext_vector_type(8))) _Float16 half8;
typedef __attribute__((ext_vector_type(4))) float f32x4;

__device__ __forceinline__ f32x4 mfma16h(half8 a, half8 b, f32x4 c) {
    return __builtin_amdgcn_mfma_f32_16x16x32_f16(a, b, c, 0, 0, 0);
}
__device__ __forceinline__ float fsigmoid(float x) { return 1.0f / (1.0f + __expf(-x)); }
__device__ __forceinline__ float ftanh(float x) {
    float e = __expf(-2.0f * fabsf(x));
    float r = (1.0f - e) / (1.0f + e);
    return copysignf(r, x);
}
// LDS-only barrier: does NOT drain vmcnt, so global prefetches stay in
// flight across it (plain __syncthreads drains vmcnt(0) -> convoy).
__device__ __forceinline__ void bar_lds() {
    asm volatile("s_waitcnt lgkmcnt(0)" ::: "memory");
    __builtin_amdgcn_sched_barrier(0);
    __builtin_amdgcn_s_barrier();
    __builtin_amdgcn_sched_barrier(0);
}

// ---------------- ew0: pure function of x, fully parallel, fp32 ------------
__global__ void ew0k(const float* __restrict__ x, const float* __restrict__ Wev0,
                     const float* __restrict__ bev0, float* __restrict__ ew0p) {
    int idx = blockIdx.x * 256 + threadIdx.x;          // = b*T + t
    int t = idx & (Tsz - 1);
    float e = 0.0f;
    if (t > 0) {
        const float* xc = x + (size_t)idx * INsz;
        const float* xp = xc - INsz;
        float acc = bev0[0];
#pragma unroll
        for (int k = 0; k < INsz; ++k) acc += xc[k] * Wev0[k] + xp[k] * Wev0[INsz + k];
        e = fsigmoid(acc);
    }
    ew0p[idx] = e;
}

// ---------------- weight fragment prep: split-2 fp16 B-fragments ------------
// layout: dst[ ((tile*KC + kc)*2 + split)*512 + lane*8 + j ]
__global__ void prep_frag(const float* __restrict__ W, _Float16* __restrict__ dst, int KC) {
    int tile = blockIdx.x / KC, kc = blockIdx.x % KC;
    int lane = threadIdx.x;
    int n16 = lane & 15, q = lane >> 4;
#pragma unroll
    for (int j = 0; j < 8; ++j) {
        int k = kc * 32 + q * 8 + j;
        float wv = W[(size_t)k * Hsz + tile * 16 + n16];
        _Float16 hi = (_Float16)wv;
        _Float16 lo = (_Float16)(wv - (float)hi);
        size_t rec = ((size_t)tile * KC + kc) * 2;
        dst[(rec + 0) * 512 + lane * 8 + j] = hi;
        dst[(rec + 1) * 512 + lane * 8 + j] = lo;
    }
}

// ---------------- fused pipelined kernel ------------------------------------
// Launch L processes: role K0 -> chunk L, roles KB/EW1 -> chunk L-1,
// role K1 -> chunk L-2. Cross-launch stream ordering provides all deps;
// roles within one launch are mutually independent (ping-pong buffers).
__global__ __launch_bounds__(512, 2) void fused(
    const float* __restrict__ x, const float* __restrict__ ew0p, float* __restrict__ ew1p,
    const _Float16* __restrict__ fA0, const _Float16* __restrict__ fR0, const _Float16* __restrict__ fI0,
    const _Float16* __restrict__ fA1, const _Float16* __restrict__ fR1,
    const _Float16* __restrict__ fI1, const _Float16* __restrict__ fS1,
    const float* __restrict__ bin0, const float* __restrict__ brec0, const float* __restrict__ battn0,
    const float* __restrict__ tau0, const float* __restrict__ gamma0, const float* __restrict__ beta0,
    const float* __restrict__ bin1, const float* __restrict__ brec1, const float* __restrict__ battn1,
    const float* __restrict__ tau1, const float* __restrict__ gamma1, const float* __restrict__ beta1,
    const float* __restrict__ bskip, const float* __restrict__ Wev1, const float* __restrict__ bev1,
    _Float16* __restrict__ h0nA, _Float16* __restrict__ h0nB,
    float* __restrict__ in1bA, float* __restrict__ in1bB,
    float* __restrict__ skpbA, float* __restrict__ skpbB,
    float* __restrict__ h1s, int C, int L, int nch) {

    __shared__ _Float16 sAh[4096], sAl[4096];   // h0n_{t-1} / gated-h (reused)
    __shared__ _Float16 sW[65536];              // attn hi plane, 128 KB
    __shared__ float red[16][8][2];

    const int tid = threadIdx.x;
    const int w = tid >> 6, lane = tid & 63;
    const int n16 = lane & 15, q = lane >> 4;
    const int bx = blockIdx.x;

    if (bx < 32) {
        // ================= role K0: layer-0 recurrence, chunk L ============
        const int ci = L;
        if (ci >= nch) return;
        _Float16* __restrict__ h0n = (ci & 1) ? h0nB : h0nA;
        const _Float16* __restrict__ h0prev = (ci & 1) ? h0nA : h0nB;
        const int t0 = ci * C;
        const int rb = bx;
        const int r0 = rb * 16;
        const int c0 = w * 16 + n16, c1 = c0 + 128;

        for (int i = tid; i < 8192; i += 512) {
            int rec = i >> 6, off = i & 63;
            ((int4*)sW)[i] = ((const int4*)(fA0 + (size_t)rec * 2 * 512))[off];
        }
        half8 rB[2][8][2];
#pragma unroll
        for (int t2 = 0; t2 < 2; ++t2) {
            const int tile = t2 ? w + 8 : w;
#pragma unroll
            for (int kc = 0; kc < 8; ++kc) {
#pragma unroll
                for (int sp = 0; sp < 2; ++sp)
                    rB[t2][kc][sp] = *(const half8*)(fR0 + (((size_t)tile * 8 + kc) * 2 + sp) * 512 + lane * 8);
            }
        }
        half8 iB[2][2];
#pragma unroll
        for (int t2 = 0; t2 < 2; ++t2) {
            const int tile = t2 ? w + 8 : w;
#pragma unroll
            for (int sp = 0; sp < 2; ++sp)
                iB[t2][sp] = *(const half8*)(fI0 + ((size_t)tile * 2 + sp) * 512 + lane * 8);
        }
        float cbi[2], cbr[2], cba[2], ctau[2], cg[2], cb[2];
#pragma unroll
        for (int t2 = 0; t2 < 2; ++t2) {
            const int col = t2 ? c1 : c0;
            cbi[t2] = bin0[col]; cbr[t2] = brec0[col]; cba[t2] = battn0[col];
            ctau[t2] = 0.1f / fminf(fmaxf(tau0[col], 0.1f), 10.0f);
            cg[t2] = gamma0[col]; cb[t2] = beta0[col];
        }
        // init: prev-buffer slot C = h0 state at t0-1; copy to slot 0 of cur
        {
            const int4* src = (const int4*)(h0prev + ((size_t)C * 32 + rb) * 8192);
            int4 vh = src[tid], vl = src[tid + 512];
            ((int4*)sAh)[tid] = vh; ((int4*)sAl)[tid] = vl;
            int4* dst0 = (int4*)(h0n + (size_t)rb * 8192);
            dst0[tid] = vh; dst0[tid + 512] = vl;
        }
        __syncthreads();
        float h0reg[2][4];
#pragma unroll
        for (int t2 = 0; t2 < 2; ++t2) {
            const int col = t2 ? c1 : c0;
#pragma unroll
            for (int r = 0; r < 4; ++r) {
                int idx = ((col >> 3) * 16 + (q * 4 + r)) * 8 + (col & 7);
                h0reg[t2][r] = (float)sAh[idx] + (float)sAl[idx];
            }
        }
        auto pw = [&](int row, int col, float v) {
            int idx = ((col >> 3) * 16 + row) * 8 + (col & 7);
            _Float16 h = (_Float16)v;
            sAh[idx] = h;
            sAl[idx] = (_Float16)(v - (float)h);
        };

        const float* xbase = x + (size_t)(r0 + n16) * Tsz * INsz;
        const _Float16* lo0 = fA0 + ((size_t)w * 8 * 2 + 1) * 512 + lane * 8;         // tile w, kc stride 2*512
        const _Float16* lo1 = fA0 + (((size_t)(w + 8) * 8) * 2 + 1) * 512 + lane * 8; // tile w+8

        // software pipeline: x raw float4 and ew0 loaded 1 step ahead
        float4 xv0 = *(const float4*)(xbase + (size_t)t0 * INsz + q * 8);
        float4 xv1 = *(const float4*)(xbase + (size_t)t0 * INsz + q * 8 + 4);
        float e0r[4];
#pragma unroll
        for (int r = 0; r < 4; ++r)
            e0r[r] = ew0p[(size_t)(r0 + q * 4 + r) * Tsz + t0];

#pragma unroll 1
        for (int s = 0; s < C; ++s) {
            const int t = t0 + s;
            // convert prefetched x(t), then issue x(t+1)
            half8 xh, xl;
            {
                float xv[8] = {xv0.x, xv0.y, xv0.z, xv0.w, xv1.x, xv1.y, xv1.z, xv1.w};
#pragma unroll
                for (int j = 0; j < 8; ++j) {
                    _Float16 h = (_Float16)xv[j];
                    xh[j] = h;
                    xl[j] = (_Float16)(xv[j] - (float)h);
                }
            }
            if (s + 1 < C) {
                const float* xp = xbase + (size_t)(t + 1) * INsz + q * 8;
                xv0 = *(const float4*)xp;
                xv1 = *(const float4*)(xp + 4);
            }
            // ---- mm_attn: A = sA pair (h0n_{t-1}), Bhi = LDS, Blo streamed ----
            f32x4 aA0 = {0,0,0,0}, aA1 = {0,0,0,0};
            {
                half8 nl0 = *(const half8*)(lo0);
                half8 nl1 = *(const half8*)(lo1);
#pragma unroll
                for (int kc = 0; kc < 8; ++kc) {
                    half8 cl0 = nl0, cl1 = nl1;
                    if (kc < 7) {
                        nl0 = *(const half8*)(lo0 + (size_t)(kc + 1) * 2 * 512);
                        nl1 = *(const half8*)(lo1 + (size_t)(kc + 1) * 2 * 512);
                    }
                    half8 ah = *(const half8*)&sAh[((kc * 4 + q) * 16 + n16) * 8];
                    half8 al = *(const half8*)&sAl[((kc * 4 + q) * 16 + n16) * 8];
                    half8 bh0 = *(const half8*)&sW[((w * 8 + kc) * 512) + lane * 8];
                    half8 bh1 = *(const half8*)&sW[(((w + 8) * 8 + kc) * 512) + lane * 8];
                    aA0 = mfma16h(ah, bh0, aA0); aA1 = mfma16h(ah, bh1, aA1);
                    aA0 = mfma16h(al, bh0, aA0); aA1 = mfma16h(al, bh1, aA1);
                    aA0 = mfma16h(ah, cl0, aA0); aA1 = mfma16h(ah, cl1, aA1);
                    aA0 = mfma16h(al, cl0, aA0); aA1 = mfma16h(al, cl1, aA1);
                }
            }
            // ---- inp = x @ Win0 (registers) ----
            f32x4 aI0 = {0,0,0,0}, aI1 = {0,0,0,0};
            aI0 = mfma16h(xh, iB[0][0], aI0); aI1 = mfma16h(xh, iB[1][0], aI1);
            aI0 = mfma16h(xl, iB[0][0], aI0); aI1 = mfma16h(xl, iB[1][0], aI1);
            aI0 = mfma16h(xh, iB[0][1], aI0); aI1 = mfma16h(xh, iB[1][1], aI1);
            aI0 = mfma16h(xl, iB[0][1], aI0); aI1 = mfma16h(xl, iB[1][1], aI1);
            bar_lds();   // B1: mm_attn LDS reads complete
            // gate: overwrite sA with h0*sigmoid(attn)
#pragma unroll
            for (int r = 0; r < 4; ++r) {
                const int row = q * 4 + r;
                pw(row, c0, h0reg[0][r] * fsigmoid(aA0[r] + cba[0]));
                pw(row, c1, h0reg[1][r] * fsigmoid(aA1[r] + cba[1]));
            }
            bar_lds();   // B2
            // ---- mm_rec: A = gated pair, B = registers ----
            f32x4 aR0 = {0,0,0,0}, aR1 = {0,0,0,0};
#pragma unroll
            for (int kc = 0; kc < 8; ++kc) {
                half8 ah = *(const half8*)&sAh[((kc * 4 + q) * 16 + n16) * 8];
                half8 al = *(const half8*)&sAl[((kc * 4 + q) * 16 + n16) * 8];
                aR0 = mfma16h(ah, rB[0][kc][0], aR0); aR1 = mfma16h(ah, rB[1][kc][0], aR1);
                aR0 = mfma16h(al, rB[0][kc][0], aR0); aR1 = mfma16h(al, rB[1][kc][0], aR1);
                aR0 = mfma16h(ah, rB[0][kc][1], aR0); aR1 = mfma16h(ah, rB[1][kc][1], aR1);
                aR0 = mfma16h(al, rB[0][kc][1], aR0); aR1 = mfma16h(al, rB[1][kc][1], aR1);
            }
            float cell[2][4];
#pragma unroll
            for (int r = 0; r < 4; ++r) {
                float i0 = ftanh(aI0[r] + cbi[0]);
                float i1 = ftanh(aI1[r] + cbi[1]);
                float g0 = ftanh(aR0[r] + cbr[0]);
                float g1 = ftanh(aR1[r] + cbr[1]);
                float ef = 1.0f + e0r[r];
                cell[0][r] = h0reg[0][r] + ctau[0] * ef * (i0 + g0 - h0reg[0][r]);
                cell[1][r] = h0reg[1][r] + ctau[1] * ef * (i1 + g1 - h0reg[1][r]);
            }
            // prefetch next-step ew0 (stays in flight across bar_lds)
            if (s + 1 < C) {
#pragma unroll
                for (int r = 0; r < 4; ++r)
                    e0r[r] = ew0p[(size_t)(r0 + q * 4 + r) * Tsz + t + 1];
            }
#pragma unroll
            for (int r = 0; r < 4; ++r) {
                float pr = cell[0][r] + cell[1][r];
                float p2 = cell[0][r] * cell[0][r] + cell[1][r] * cell[1][r];
#pragma unroll
                for (int off = 1; off < 16; off <<= 1) {
                    pr += __shfl_xor(pr, off, 64);
                    p2 += __shfl_xor(p2, off, 64);
                }
                if (n16 == 0) { red[q * 4 + r][w][0] = pr; red[q * 4 + r][w][1] = p2; }
            }
            bar_lds();   // B3: red ready
            float lnm[4], lnr[4];
#pragma unroll
            for (int r = 0; r < 4; ++r) {
                const int row = q * 4 + r;
                float S = 0.0f, Q2 = 0.0f;
#pragma unroll
                for (int wv = 0; wv < 8; ++wv) { S += red[row][wv][0]; Q2 += red[row][wv][1]; }
                float mu = S * (1.0f / 256.0f);
                float var = Q2 * (1.0f / 256.0f) - mu * mu;
                lnm[r] = mu;
                lnr[r] = 1.0f / sqrtf(var + 1e-5f);
            }
#pragma unroll
            for (int r = 0; r < 4; ++r) {
                const int row = q * 4 + r;
                float h0v = (cell[0][r] - lnm[r]) * lnr[r] * cg[0] + cb[0];
                float h1v = (cell[1][r] - lnm[r]) * lnr[r] * cg[1] + cb[1];
                pw(row, c0, h0v); pw(row, c1, h1v);
                h0reg[0][r] = h0v; h0reg[1][r] = h1v;
            }
            bar_lds();   // B4: sA = h0n_t
            int4* d = (int4*)(h0n + ((size_t)(s + 1) * 32 + rb) * 8192);
            d[tid] = ((const int4*)sAh)[tid];
            d[tid + 512] = ((const int4*)sAl)[tid];
        }
    } else if (bx < 64) {
        // ================= role K1: layer-1 recurrence, chunk L-2 ==========
        const int ci = L - 2;
        if (ci < 0) return;
        const float* __restrict__ in1b = (ci & 1) ? in1bB : in1bA;
        const float* __restrict__ skpb = (ci & 1) ? skpbB : skpbA;
        const int t0 = ci * C;
        const int rb = bx - 32;
        const int r0 = rb * 16;
        const int c0 = w * 16 + n16, c1 = c0 + 128;

        for (int i = tid; i < 8192; i += 512) {
            int rec = i >> 6, off = i & 63;
            ((int4*)sW)[i] = ((const int4*)(fA1 + (size_t)rec * 2 * 512))[off];
        }
        half8 rB[2][8][2];
#pragma unroll
        for (int t2 = 0; t2 < 2; ++t2) {
            const int tile = t2 ? w + 8 : w;
#pragma unroll
            for (int kc = 0; kc < 8; ++kc) {
#pragma unroll
                for (int sp = 0; sp < 2; ++sp)
                    rB[t2][kc][sp] = *(const half8*)(fR1 + (((size_t)tile * 8 + kc) * 2 + sp) * 512 + lane * 8);
            }
        }
        float cbr[2], cba[2], ctau[2], cg[2], cb[2];
#pragma unroll
        for (int t2 = 0; t2 < 2; ++t2) {
            const int col = t2 ? c1 : c0;
            cbr[t2] = brec1[col]; cba[t2] = battn1[col];
            ctau[t2] = 0.1f / fminf(fmaxf(tau1[col], 0.1f), 10.0f);
            cg[t2] = gamma1[col]; cb[t2] = beta1[col];
        }
        float h1reg[2][4];
#pragma unroll
        for (int t2 = 0; t2 < 2; ++t2) {
            const int col = t2 ? c1 : c0;
#pragma unroll
            for (int r = 0; r < 4; ++r) {
                const int row = q * 4 + r;
                float hv = h1s[(size_t)(r0 + row) * Hsz + col];
                h1reg[t2][r] = hv;
                int idx = ((col >> 3) * 16 + row) * 8 + (col & 7);
                _Float16 h = (_Float16)hv;
                sAh[idx] = h;
                sAl[idx] = (_Float16)(hv - (float)h);
            }
        }
        __syncthreads();

        auto pw = [&](int row, int col, float v) {
            int idx = ((col >> 3) * 16 + row) * 8 + (col & 7);
            _Float16 h = (_Float16)v;
            sAh[idx] = h;
            sAl[idx] = (_Float16)(v - (float)h);
        };
        const _Float16* lo0 = fA1 + ((size_t)w * 8 * 2 + 1) * 512 + lane * 8;
        const _Float16* lo1 = fA1 + (((size_t)(w + 8) * 8) * 2 + 1) * 512 + lane * 8;

        float e1r[4];
#pragma unroll
        for (int r = 0; r < 4; ++r)
            e1r[r] = ew1p[(size_t)(r0 + q * 4 + r) * Tsz + t0];

#pragma unroll 1
        for (int s = 0; s < C; ++s) {
            const int t = t0 + s;
            // early loads: in1 / skip (consumed after mm_rec, ~2 phases later)
            float iv[2][4], sv[2][4];
#pragma unroll
            for (int r = 0; r < 4; ++r) {
                const int row = q * 4 + r;
                size_t i0 = ((size_t)s * Bsz + r0 + row) * Hsz + c0;
                size_t i1 = ((size_t)s * Bsz + r0 + row) * Hsz + c1;
                iv[0][r] = in1b[i0]; iv[1][r] = in1b[i1];
                sv[0][r] = skpb[i0]; sv[1][r] = skpb[i1];
            }
            // ---- mm_attn1: A = sA pair (h1_{t-1}) ----
            f32x4 aA0 = {0,0,0,0}, aA1 = {0,0,0,0};
            {
                half8 nl0 = *(const half8*)(lo0);
                half8 nl1 = *(const half8*)(lo1);
#pragma unroll
                for (int kc = 0; kc < 8; ++kc) {
                    half8 cl0 = nl0, cl1 = nl1;
                    if (kc < 7) {
                        nl0 = *(const half8*)(lo0 + (size_t)(kc + 1) * 2 * 512);
                        nl1 = *(const half8*)(lo1 + (size_t)(kc + 1) * 2 * 512);
                    }
                    half8 ah = *(const half8*)&sAh[((kc * 4 + q) * 16 + n16) * 8];
                    half8 al = *(const half8*)&sAl[((kc * 4 + q) * 16 + n16) * 8];
                    half8 bh0 = *(const half8*)&sW[((w * 8 + kc) * 512) + lane * 8];
                    half8 bh1 = *(const half8*)&sW[(((w + 8) * 8 + kc) * 512) + lane * 8];
                    aA0 = mfma16h(ah, bh0, aA0); aA1 = mfma16h(ah, bh1, aA1);
                    aA0 = mfma16h(al, bh0, aA0); aA1 = mfma16h(al, bh1, aA1);
                    aA0 = mfma16h(ah, cl0, aA0); aA1 = mfma16h(ah, cl1, aA1);
                    aA0 = mfma16h(al, cl0, aA0); aA1 = mfma16h(al, cl1, aA1);
                }
            }
            bar_lds();   // B1
#pragma unroll
            for (int r = 0; r < 4; ++r) {
                const int row = q * 4 + r;
                pw(row, c0, h1reg[0][r] * fsigmoid(aA0[r] + cba[0]));
                pw(row, c1, h1reg[1][r] * fsigmoid(aA1[r] + cba[1]));
            }
            bar_lds();   // B2
            f32x4 aR0 = {0,0,0,0}, aR1 = {0,0,0,0};
#pragma unroll
            for (int kc = 0; kc < 8; ++kc) {
                half8 ah = *(const half8*)&sAh[((kc * 4 + q) * 16 + n16) * 8];
                half8 al = *(const half8*)&sAl[((kc * 4 + q) * 16 + n16) * 8];
                aR0 = mfma16h(ah, rB[0][kc][0], aR0); aR1 = mfma16h(ah, rB[1][kc][0], aR1);
                aR0 = mfma16h(al, rB[0][kc][0], aR0); aR1 = mfma16h(al, rB[1][kc][0], aR1);
                aR0 = mfma16h(ah, rB[0][kc][1], aR0); aR1 = mfma16h(ah, rB[1][kc][1], aR1);
                aR0 = mfma16h(al, rB[0][kc][1], aR0); aR1 = mfma16h(al, rB[1][kc][1], aR1);
            }
            float cell[2][4];
#pragma unroll
            for (int r = 0; r < 4; ++r) {
                float g0 = ftanh(aR0[r] + cbr[0]);
                float g1 = ftanh(aR1[r] + cbr[1]);
                float ef = 1.0f + e1r[r];
                cell[0][r] = h1reg[0][r] + ctau[0] * ef * (iv[0][r] + g0 - h1reg[0][r]);
                cell[1][r] = h1reg[1][r] + ctau[1] * ef * (iv[1][r] + g1 - h1reg[1][r]);
            }
            if (s + 1 < C) {
#pragma unroll
                for (int r = 0; r < 4; ++r)
                    e1r[r] = ew1p[(size_t)(r0 + q * 4 + r) * Tsz + t + 1];
            }
#pragma unroll
            for (int r = 0; r < 4; ++r) {
                float pr = cell[0][r] + cell[1][r];
                float p2 = cell[0][r] * cell[0][r] + cell[1][r] * cell[1][r];
#pragma unroll
                for (int off = 1; off < 16; off <<= 1) {
                    pr += __shfl_xor(pr, off, 64);
                    p2 += __shfl_xor(p2, off, 64);
                }
                if (n16 == 0) { red[q * 4 + r][w][0] = pr; red[q * 4 + r][w][1] = p2; }
            }
            bar_lds();   // B3
            float lnm[4], lnr[4];
#pragma unroll
            for (int r = 0; r < 4; ++r) {
                const int row = q * 4 + r;
                float S = 0.0f, Q2 = 0.0f;
#pragma unroll
                for (int wv = 0; wv < 8; ++wv) { S += red[row][wv][0]; Q2 += red[row][wv][1]; }
                float mu = S * (1.0f / 256.0f);
                float var = Q2 * (1.0f / 256.0f) - mu * mu;
                lnm[r] = mu;
                lnr[r] = 1.0f / sqrtf(var + 1e-5f);
            }
#pragma unroll
            for (int r = 0; r < 4; ++r) {
                const int row = q * 4 + r;
                float h0v = (cell[0][r] - lnm[r]) * lnr[r] * cg[0] + cb[0] + sv[0][r];
                float h1v = (cell[1][r] - lnm[r]) * lnr[r] * cg[1] + cb[1] + sv[1][r];
                pw(row, c0, h0v); pw(row, c1, h1v);
                h1reg[0][r] = h0v; h1reg[1][r] = h1v;
            }
            bar_lds();   // B4
        }
        // persist fp32 h1 state
#pragma unroll
        for (int t2 = 0; t2 < 2; ++t2) {
            const int col = t2 ? c1 : c0;
#pragma unroll
            for (int r = 0; r < 4; ++r)
                h1s[(size_t)(r0 + q * 4 + r) * Hsz + col] = h1reg[t2][r];
        }
    } else if (bx < 64 + C * 4) {
        // ================= role KB: in1/skip GEMMs, chunk L-1 ==============
        const int ci = L - 1;
        if (ci < 0 || ci >= nch) return;
        const _Float16* __restrict__ h0n = (ci & 1) ? h0nB : h0nA;
        float* __restrict__ in1b = (ci & 1) ? in1bB : in1bA;
        float* __restrict__ skpb = (ci & 1) ? skpbB : skpbA;
        const int bi = bx - 64;
        const int sbase = (bi >> 5) * 8;
        const int rb = bi & 31;
        const int r0 = rb * 16;
        const int c0 = w * 16 + n16, c1 = c0 + 128;
        float cbi[2], cbs[2];
#pragma unroll
        for (int t2 = 0; t2 < 2; ++t2) {
            const int col = t2 ? c1 : c0;
            cbi[t2] = bin1[col]; cbs[t2] = bskip[col];
        }
        for (int i = 0; i < 8; ++i) {
            const int s = sbase + i;
            const _Float16* abase = h0n + ((size_t)(s + 1) * 32 + rb) * 8192;
            f32x4 aI0 = {0,0,0,0}, aI1 = {0,0,0,0}, aS0 = {0,0,0,0}, aS1 = {0,0,0,0};
#pragma unroll
            for (int kc = 0; kc < 8; ++kc) {
                half8 ah = *(const half8*)&abase[((kc * 4 + q) * 16 + n16) * 8];
                half8 al = *(const half8*)&abase[4096 + ((kc * 4 + q) * 16 + n16) * 8];
                size_t o0 = (((size_t)w * 8 + kc) * 2) * 512 + lane * 8;
                size_t o1 = (((size_t)(w + 8) * 8 + kc) * 2) * 512 + lane * 8;
                half8 bh0 = *(const half8*)(fI1 + o0), bl0 = *(const half8*)(fI1 + o0 + 512);
                half8 bh1 = *(const half8*)(fI1 + o1), bl1 = *(const half8*)(fI1 + o1 + 512);
                aI0 = mfma16h(ah, bh0, aI0); aI1 = mfma16h(ah, bh1, aI1);
                aI0 = mfma16h(al, bh0, aI0); aI1 = mfma16h(al, bh1, aI1);
                aI0 = mfma16h(ah, bl0, aI0); aI1 = mfma16h(ah, bl1, aI1);
                aI0 = mfma16h(al, bl0, aI0); aI1 = mfma16h(al, bl1, aI1);
                half8 ch0 = *(const half8*)(fS1 + o0), cl0 = *(const half8*)(fS1 + o0 + 512);
                half8 ch1 = *(const half8*)(fS1 + o1), cl1 = *(const half8*)(fS1 + o1 + 512);
                aS0 = mfma16h(ah, ch0, aS0); aS1 = mfma16h(ah, ch1, aS1);
                aS0 = mfma16h(al, ch0, aS0); aS1 = mfma16h(al, ch1, aS1);
                aS0 = mfma16h(ah, cl0, aS0); aS1 = mfma16h(ah, cl1, aS1);
                aS0 = mfma16h(al, cl0, aS0); aS1 = mfma16h(al, cl1, aS1);
            }
#pragma unroll
            for (int r = 0; r < 4; ++r) {
                const int row = q * 4 + r;
                size_t i0 = ((size_t)s * Bsz + r0 + row) * Hsz + c0;
                size_t i1 = ((size_t)s * Bsz + r0 + row) * Hsz + c1;
                in1b[i0] = ftanh(aI0[r] + cbi[0]);
                in1b[i1] = ftanh(aI1[r] + cbi[1]);
                skpb[i0] = aS0[r] + cbs[0];
                skpb[i1] = aS1[r] + cbs[1];
            }
        }
    } else {
        // ================= role EW1: event weights, chunk L-1 ==============
        const int ci = L - 1;
        if (ci < 0 || ci >= nch) return;
        const _Float16* __restrict__ h0n = (ci & 1) ? h0nB : h0nA;
        const int t0 = ci * C;
        const int bi = bx - 64 - C * 4;
        const int wid = bi * 8 + w;
        const int s = wid >> 5, rb = wid & 31;
        float acc = 0.0f;
#pragma unroll
        for (int half = 0; half < 2; ++half) {
            const _Float16* base = h0n + ((size_t)(half ? s : s + 1) * 32 + rb) * 8192;
#pragma unroll
            for (int kc = 0; kc < 8; ++kc) {
                half8 ah = *(const half8*)&base[((kc * 4 + q) * 16 + n16) * 8];
                half8 al = *(const half8*)&base[4096 + ((kc * 4 + q) * 16 + n16) * 8];
                const float* wv = Wev1 + half * 256 + kc * 32 + q * 8;
#pragma unroll
                for (int j = 0; j < 8; ++j)
                    acc += ((float)ah[j] + (float)al[j]) * wv[j];
            }
        }
        acc += __shfl_xor(acc, 16, 64);
        acc += __shfl_xor(acc, 32, 64);
        const int t = t0 + s;
        if (q == 0) {
            float e = (t > 0) ? fsigmoid(acc + bev1[0]) : 0.0f;
            ew1p[(size_t)(rb * 16 + n16) * Tsz + t] = e;
        }
    }
}

// ---------------- out = h1_final @ Wout + bout ------------------------------
__global__ void outk(const float* __restrict__ h1s, const float* __restrict__ Wout,
                     const float* __restrict__ bout, float* __restrict__ outp) {
    const int w = threadIdx.x >> 6, lane = threadIdx.x & 63;
    const int b = blockIdx.x * 4 + w;
    float4 hv = *(const float4*)(h1s + (size_t)b * Hsz + lane * 4);
    float4 wv = *(const float4*)(Wout + lane * 4);
    float acc = hv.x * wv.x + hv.y * wv.y + hv.z * wv.z + hv.w * wv.w;
#pragma unroll
    for (int off = 1; off < 64; off <<= 1) acc += __shfl_xor(acc, off, 64);
    if (lane == 0) outp[b] = acc + bout[0];
}

extern "C" void kernel_launch(void* const* d_in, const int* in_sizes, int n_in,
                              void* d_out, int out_size, void* d_ws, size_t ws_size,
                              hipStream_t stream) {
    const float* x      = (const float*)d_in[0];
    const float* Win0   = (const float*)d_in[1];
    const float* bin0   = (const float*)d_in[2];
    const float* Wrec0  = (const float*)d_in[3];
    const float* brec0  = (const float*)d_in[4];
    const float* Wattn0 = (const float*)d_in[5];
    const float* battn0 = (const float*)d_in[6];
    const float* Wev0   = (const float*)d_in[7];
    const float* bev0   = (const float*)d_in[8];
    const float* tau0   = (const float*)d_in[9];
    const float* gamma0 = (const float*)d_in[10];
    const float* beta0  = (const float*)d_in[11];
    const float* Win1   = (const float*)d_in[12];
    const float* bin1   = (const float*)d_in[13];
    const float* Wrec1  = (const float*)d_in[14];
    const float* brec1  = (const float*)d_in[15];
    const float* Wattn1 = (const float*)d_in[16];
    const float* battn1 = (const float*)d_in[17];
    const float* Wev1   = (const float*)d_in[18];
    const float* bev1   = (const float*)d_in[19];
    const float* tau1   = (const float*)d_in[20];
    const float* gamma1 = (const float*)d_in[21];
    const float* beta1  = (const float*)d_in[22];
    const float* Wskip  = (const float*)d_in[23];
    const float* bskip  = (const float*)d_in[24];
    const float* Wout   = (const float*)d_in[25];
    const float* bout   = (const float*)d_in[26];

    float* outp = (float*)d_out;
    float* ew0p = outp + Bsz;                       // ew0 [B,T]
    float* ew1p = ew0p + (size_t)Bsz * Tsz;         // ew1 [B,T]

    // ---- workspace layout ----
    // fragments | h0n x2 (ping-pong) | in1b x2 | skpb x2 | h1s
    _Float16* p = (_Float16*)d_ws;
    _Float16* fA0 = p; p += 131072;
    _Float16* fR0 = p; p += 131072;
    _Float16* fA1 = p; p += 131072;
    _Float16* fR1 = p; p += 131072;
    _Float16* fI1 = p; p += 131072;
    _Float16* fS1 = p; p += 131072;
    _Float16* fI0 = p; p += 16384;
    size_t frag_bytes = (size_t)(6 * 131072 + 16384) * 2;

    int C = 128;
    while (C > 16) {
        size_t need = frag_bytes
                    + 2 * ((size_t)(C + 1) * 524288)   // h0n x2
                    + 4 * ((size_t)C * 524288)          // in1b x2 + skpb x2
                    + 524288;                           // h1s
        if (need <= ws_size) break;
        C >>= 1;
    }
    char* qp = (char*)d_ws + frag_bytes;
    _Float16* h0nA = (_Float16*)qp; qp += (size_t)(C + 1) * 524288;
    _Float16* h0nB = (_Float16*)qp; qp += (size_t)(C + 1) * 524288;
    float* in1bA = (float*)qp;      qp += (size_t)C * 524288;
    float* in1bB = (float*)qp;      qp += (size_t)C * 524288;
    float* skpbA = (float*)qp;      qp += (size_t)C * 524288;
    float* skpbB = (float*)qp;      qp += (size_t)C * 524288;
    float* h1s = (float*)qp;
    (void)in_sizes; (void)n_in; (void)out_size;

    // chunk 0 reads its init state from h0nB slot C -> zero it; zero h1 state
    hipMemsetAsync(h0nB + (size_t)C * 32 * 8192, 0, 524288, stream);
    hipMemsetAsync(h1s, 0, 524288, stream);

    ew0k<<<(Bsz * Tsz) / 256, 256, 0, stream>>>(x, Wev0, bev0, ew0p);
    prep_frag<<<16 * 8, 64, 0, stream>>>(Wattn0, fA0, 8);
    prep_frag<<<16 * 8, 64, 0, stream>>>(Wrec0,  fR0, 8);
    prep_frag<<<16 * 8, 64, 0, stream>>>(Wattn1, fA1, 8);
    prep_frag<<<16 * 8, 64, 0, stream>>>(Wrec1,  fR1, 8);
    prep_frag<<<16 * 8, 64, 0, stream>>>(Win1,   fI1, 8);
    prep_frag<<<16 * 8, 64, 0, stream>>>(Wskip,  fS1, 8);
    prep_frag<<<16 * 1, 64, 0, stream>>>(Win0,   fI0, 1);

    const int nch = Tsz / C;
    const int grid = 64 + C * 8;    // 32 k0 + 32 k1 + 4C kb + 4C ew1
    for (int L = 0; L < nch + 2; ++L) {
        fused<<<grid, 512, 0, stream>>>(
            x, ew0p, ew1p, fA0, fR0, fI0, fA1, fR1, fI1, fS1,
            bin0, brec0, battn0, tau0, gamma0, beta0,
            bin1, brec1, battn1, tau1, gamma1, beta1,
            bskip, Wev1, bev1,
            h0nA, h0nB, in1bA, in1bB, skpbA, skpbB, h1s, C, L, nch);
    }
    outk<<<Bsz / 4, 256, 0, stream>>>(h1s, Wout, bout, outp);
}